// Round 17
// baseline (419.478 us; speedup 1.0000x reference)
//
#include <hip/hip_runtime.h>
#include <hip/hip_bf16.h>
#include <cstdint>
#include <cstddef>

typedef unsigned short u16;
typedef __bf16 bf16x8 __attribute__((ext_vector_type(8)));
typedef float f32x4 __attribute__((ext_vector_type(4)));

#define D_MODEL 1024
#define D_FF    4096
#define BATCH   2
#define SEQ     2048
#define NH      16
#define HD      64
#define ROWS    (BATCH*SEQ)   // 4096
#define QKVS    3072          // packed QKV row stride

// ---------- helpers ----------
__device__ __forceinline__ u16 f2bf(float f) {
    union { float f; uint32_t u; } v; v.f = f;
    uint32_t u = v.u;
    u += 0x7FFF + ((u >> 16) & 1);   // RNE
    return (u16)(u >> 16);
}

__device__ __forceinline__ float bf2f(u16 u) {
    union { uint32_t u; float f; } v; v.u = (uint32_t)u << 16;
    return v.f;
}

__device__ __forceinline__ uint32_t cvtpk_bf16(float lo, float hi) {
    uint32_t r;
    asm("v_cvt_pk_bf16_f32 %0, %1, %2" : "=v"(r) : "v"(lo), "v"(hi));
    return r;
}

__device__ __forceinline__ bf16x8 ldg8(const u16* p) {
    return *reinterpret_cast<const bf16x8*>(p);
}

__device__ __forceinline__ f32x4 mfma16(bf16x8 a, bf16x8 b, f32x4 c) {
    return __builtin_amdgcn_mfma_f32_16x16x32_bf16(a, b, c, 0, 0, 0);
}

__device__ __forceinline__ void gld_lds16(const void* g, void* l) {
    __builtin_amdgcn_global_load_lds(
        (const __attribute__((address_space(1))) void*)g,
        (__attribute__((address_space(3))) void*)l, 16, 0, 0);
}

// GELU, tanh-form via exp2; |err| <= ~3e-3.
__device__ __forceinline__ float gelu_f(float x) {
    float u = fmaf(0.044715f * x, x * x, x);
    float z = fminf(-2.3022036f * u, 126.0f);
    float e = __builtin_amdgcn_exp2f(z);
    return x / (1.0f + e);
}

struct alignas(8) U16x4 { u16 x, y, z, w; };

// ---------- fused prep: weight cvt (12288 blk) + LN1 (4096 blk) + bias pack (3 blk) ----------
__global__ __launch_bounds__(256) void prep(
    const float* __restrict__ s0, const float* __restrict__ s1,
    const float* __restrict__ s2, const float* __restrict__ s3,
    const float* __restrict__ s4, const float* __restrict__ s5,
    u16* __restrict__ wout,
    const float* __restrict__ x, const float* __restrict__ g1,
    const float* __restrict__ be1, u16* __restrict__ hbuf,
    const float* __restrict__ bq, const float* __restrict__ bk,
    const float* __restrict__ bv, float* __restrict__ bqkv)
{
    const size_t MM1 = 1 << 20;
    const int bid = blockIdx.x;
    const int t = threadIdx.x;

    if (bid < 12288) {
        // weight f32 -> bf16
        size_t i = (size_t)bid * 1024 + t * 4;
        const float* src; size_t off;
        if      (i <     MM1) { src = s0; off = i; }
        else if (i < 2 * MM1) { src = s1; off = i - MM1; }
        else if (i < 3 * MM1) { src = s2; off = i - 2 * MM1; }
        else if (i < 4 * MM1) { src = s3; off = i - 3 * MM1; }
        else if (i < 8 * MM1) { src = s4; off = i - 4 * MM1; }
        else                  { src = s5; off = i - 8 * MM1; }
        float4 f = *reinterpret_cast<const float4*>(src + off);
        U16x4 o{ f2bf(f.x), f2bf(f.y), f2bf(f.z), f2bf(f.w) };
        *reinterpret_cast<U16x4*>(wout + i) = o;
    } else if (bid < 12288 + ROWS) {
        // LayerNorm 1
        int row = bid - 12288;
        const float* xr = x + (size_t)row * D_MODEL;
        float4 v = *reinterpret_cast<const float4*>(xr + t * 4);
        float s = v.x + v.y + v.z + v.w;
        float q = v.x*v.x + v.y*v.y + v.z*v.z + v.w*v.w;
        #pragma unroll
        for (int off = 1; off < 64; off <<= 1) {
            s += __shfl_xor(s, off);
            q += __shfl_xor(q, off);
        }
        __shared__ float red[8];
        if ((t & 63) == 0) { red[(t >> 6) * 2] = s; red[(t >> 6) * 2 + 1] = q; }
        __syncthreads();
        float sum = red[0] + red[2] + red[4] + red[6];
        float sq  = red[1] + red[3] + red[5] + red[7];
        float mu  = sum * (1.0f / D_MODEL);
        float var = sq * (1.0f / D_MODEL) - mu * mu;
        float rstd = rsqrtf(var + 1e-6f);
        float4 gg = *reinterpret_cast<const float4*>(g1 + t * 4);
        float4 bb = *reinterpret_cast<const float4*>(be1 + t * 4);
        U16x4 o{ f2bf((v.x - mu) * rstd * gg.x + bb.x),
                 f2bf((v.y - mu) * rstd * gg.y + bb.y),
                 f2bf((v.z - mu) * rstd * gg.z + bb.z),
                 f2bf((v.w - mu) * rstd * gg.w + bb.w) };
        *reinterpret_cast<U16x4*>(hbuf + (size_t)row * D_MODEL + t * 4) = o;
    } else {
        // pack QKV bias: 3 blocks x 1024 floats
        int j = bid - (12288 + ROWS);
        const float* src = (j == 0) ? bq : (j == 1) ? bk : bv;
        float4 f = *reinterpret_cast<const float4*>(src + t * 4);
        *reinterpret_cast<float4*>(bqkv + j * 1024 + t * 4) = f;
    }
}

// ---------- LayerNorm (f32 in, bf16 out) ----------
__global__ __launch_bounds__(256) void ln_bf16(
    const float* __restrict__ x, const float* __restrict__ g,
    const float* __restrict__ b, u16* __restrict__ out)
{
    int row = blockIdx.x;
    const float* xr = x + (size_t)row * D_MODEL;
    int t = threadIdx.x;
    float4 v = *reinterpret_cast<const float4*>(xr + t * 4);
    float s = v.x + v.y + v.z + v.w;
    float q = v.x*v.x + v.y*v.y + v.z*v.z + v.w*v.w;
    #pragma unroll
    for (int off = 1; off < 64; off <<= 1) {
        s += __shfl_xor(s, off);
        q += __shfl_xor(q, off);
    }
    __shared__ float red[8];
    if ((t & 63) == 0) { red[(t >> 6) * 2] = s; red[(t >> 6) * 2 + 1] = q; }
    __syncthreads();
    float sum = red[0] + red[2] + red[4] + red[6];
    float sq  = red[1] + red[3] + red[5] + red[7];
    float mu  = sum * (1.0f / D_MODEL);
    float var = sq * (1.0f / D_MODEL) - mu * mu;
    float rstd = rsqrtf(var + 1e-6f);
    float4 gg = *reinterpret_cast<const float4*>(g + t * 4);
    float4 bb = *reinterpret_cast<const float4*>(b + t * 4);
    U16x4 o{ f2bf((v.x - mu) * rstd * gg.x + bb.x),
             f2bf((v.y - mu) * rstd * gg.y + bb.y),
             f2bf((v.z - mu) * rstd * gg.z + bb.z),
             f2bf((v.w - mu) * rstd * gg.w + bb.w) };
    *reinterpret_cast<U16x4*>(out + (size_t)row * D_MODEL + t * 4) = o;
}

#define EPI_BF16   0
#define EPI_RESF32 1
#define EPI_GELU   2
#define EPI_PART   3

// ---------- GEMM 128x128, m97-style single-buffer, 5 blocks/CU ----------
// 32 KB LDS x 5 = exactly the 160 KiB pool; VGPR 64 fits 5 waves/EU.
template<int EPI>
__global__ __launch_bounds__(256, 5) void gemm97(
    const u16* __restrict__ A, const u16* __restrict__ B,
    const float* __restrict__ bias, const float* __restrict__ res,
    u16* __restrict__ outb, float* __restrict__ outf,
    int M, int N, int K, int KS)
{
    __shared__ u16 As[128 * 64];
    __shared__ u16 Bs[128 * 64];
    const int t = threadIdx.x;
    const int lane = t & 63, w = t >> 6;
    const int lr = lane & 15, lg = lane >> 4;
    const int wrr = (w >> 1) * 64, wcc = (w & 1) * 64;
    const int brow = blockIdx.x * 128, bcol = blockIdx.y * 128;   // row-major
    const u16* Ag = A + (size_t)brow * KS;
    const u16* Bg = B + (size_t)bcol * KS;

    f32x4 acc[4][4] = {};
    const int NT = K >> 6;

    for (int kt = 0; kt < NT; ++kt) {
        #pragma unroll
        for (int c = 0; c < 4; ++c) {
            int f = c * 256 + t;
            int row = f >> 3, slot = f & 7;
            int sg = slot ^ (row & 7);
            gld_lds16(Ag + (size_t)row * KS + kt * 64 + sg * 8, As + f * 8);
            gld_lds16(Bg + (size_t)row * KS + kt * 64 + sg * 8, Bs + f * 8);
        }
        __syncthreads();

        bf16x8 af[4][2];
        #pragma unroll
        for (int mi = 0; mi < 4; ++mi) {
            int row = wrr + mi * 16 + lr;
            const u16* bp = As + row * 64;
            int key = row & 7;
            af[mi][0] = ldg8(bp + ((0 + lg) ^ key) * 8);
            af[mi][1] = ldg8(bp + ((4 + lg) ^ key) * 8);
        }
        __builtin_amdgcn_s_setprio(1);
        #pragma unroll
        for (int ni = 0; ni < 4; ++ni) {
            int row = wcc + ni * 16 + lr;
            const u16* bp = Bs + row * 64;
            int key = row & 7;
            bf16x8 b0 = ldg8(bp + ((0 + lg) ^ key) * 8);
            bf16x8 b1 = ldg8(bp + ((4 + lg) ^ key) * 8);
            #pragma unroll
            for (int mi = 0; mi < 4; ++mi) {
                acc[mi][ni] = mfma16(af[mi][0], b0, acc[mi][ni]);
                acc[mi][ni] = mfma16(af[mi][1], b1, acc[mi][ni]);
            }
        }
        __builtin_amdgcn_s_setprio(0);
        __syncthreads();
    }

    #pragma unroll
    for (int mi = 0; mi < 4; ++mi) {
        int r0 = brow + wrr + mi * 16 + lg * 4;
        #pragma unroll
        for (int ni = 0; ni < 4; ++ni) {
            int c = bcol + wcc + ni * 16 + lr;
            float bv = bias[c];
            #pragma unroll
            for (int j = 0; j < 4; ++j) {
                float v = acc[mi][ni][j] + bv;
                size_t idx = (size_t)(r0 + j) * N + c;
                if constexpr (EPI == EPI_GELU) {
                    outb[idx] = f2bf(gelu_f(v));
                } else if constexpr (EPI == EPI_RESF32) {
                    outf[idx] = v + res[idx];
                } else {
                    outb[idx] = f2bf(v);
                }
            }
        }
    }
}

// ---------- GEMM 128x128, 2-deep counted-vmcnt ----------
// RM=1: row-grouping. RM=0: col-grouping (FFN2: B L2-resident, stream A).
// EPI_PART: writes bf16 partial at outb + kz*M*N.
template<int EPI, int RM>
__global__ __launch_bounds__(256, 2) void gemm_bt(
    const u16* __restrict__ A, const u16* __restrict__ B,
    const float* __restrict__ bias, const float* __restrict__ res,
    u16* __restrict__ outb, float* __restrict__ outf,
    int M, int N, int K, int KS)
{
    __shared__ u16 As[2][128 * 64];
    __shared__ u16 Bs[2][128 * 64];
    const int t = threadIdx.x;
    const int lane = t & 63;
    const int w = t >> 6;
    const int lr = lane & 15, lg = lane >> 4;
    const int wrr = (w >> 1) * 64, wcc = (w & 1) * 64;
    const int brow = (RM ? blockIdx.x : blockIdx.y) * 128;
    const int bcol = (RM ? blockIdx.y : blockIdx.x) * 128;
    const int kz = blockIdx.z;
    const u16* Ag = A + (size_t)brow * KS + (size_t)kz * K;
    const u16* Bg = B + (size_t)bcol * KS + (size_t)kz * K;

    f32x4 acc[4][4] = {};

    const int NT = K >> 6;

    auto stage = [&](int buf, int kt) {
        const u16* ga = Ag + kt * 64;
        const u16* gb = Bg + kt * 64;
        u16* la = As[buf];
        u16* lb = Bs[buf];
        #pragma unroll
        for (int c = 0; c < 4; ++c) {
            int f = c * 256 + t;
            int row = f >> 3, slot = f & 7;
            int sg = slot ^ (row & 7);
            gld_lds16(ga + (size_t)row * KS + sg * 8, la + f * 8);
            gld_lds16(gb + (size_t)row * KS + sg * 8, lb + f * 8);
        }
    };

    auto compute = [&](int buf) {
        const u16* la = As[buf];
        const u16* lb = Bs[buf];
        bf16x8 af[4][2];
        #pragma unroll
        for (int mi = 0; mi < 4; ++mi) {
            int row = wrr + mi * 16 + lr;
            int base = row * 64;
            af[mi][0] = *reinterpret_cast<const bf16x8*>(la + base + ((0 + lg) ^ (row & 7)) * 8);
            af[mi][1] = *reinterpret_cast<const bf16x8*>(la + base + ((4 + lg) ^ (row & 7)) * 8);
        }
        __builtin_amdgcn_s_setprio(1);
        #pragma unroll
        for (int ni = 0; ni < 4; ++ni) {
            int row = wcc + ni * 16 + lr;
            int base = row * 64;
            bf16x8 b0 = *reinterpret_cast<const bf16x8*>(lb + base + ((0 + lg) ^ (row & 7)) * 8);
            bf16x8 b1 = *reinterpret_cast<const bf16x8*>(lb + base + ((4 + lg) ^ (row & 7)) * 8);
            #pragma unroll
            for (int mi = 0; mi < 4; ++mi) {
                acc[mi][ni] = mfma16(af[mi][0], b0, acc[mi][ni]);
                acc[mi][ni] = mfma16(af[mi][1], b1, acc[mi][ni]);
            }
        }
        __builtin_amdgcn_s_setprio(0);
    };

    stage(0, 0);
    if (NT > 1) {
        stage(1, 1);
        asm volatile("s_waitcnt vmcnt(8)" ::: "memory");
    } else {
        asm volatile("s_waitcnt vmcnt(0)" ::: "memory");
    }
    __builtin_amdgcn_s_barrier();

    for (int kt = 0; kt < NT; ++kt) {
        compute(kt & 1);
        if (kt + 1 == NT) break;
        __builtin_amdgcn_s_barrier();
        if (kt + 2 < NT) {
            stage(kt & 1, kt + 2);
            asm volatile("s_waitcnt vmcnt(8)" ::: "memory");
        } else {
            asm volatile("s_waitcnt vmcnt(0)" ::: "memory");
        }
        __builtin_amdgcn_s_barrier();
    }

    #pragma unroll
    for (int mi = 0; mi < 4; ++mi) {
        int r0 = brow + wrr + mi * 16 + lg * 4;
        #pragma unroll
        for (int ni = 0; ni < 4; ++ni) {
            int c = bcol + wcc + ni * 16 + lr;
            float bv = 0.f;
            if constexpr (EPI != EPI_PART) bv = bias[c];
            #pragma unroll
            for (int j = 0; j < 4; ++j) {
                float v = acc[mi][ni][j] + bv;
                size_t idx = (size_t)(r0 + j) * N + c;
                if constexpr (EPI == EPI_GELU) {
                    outb[idx] = f2bf(gelu_f(v));
                } else if constexpr (EPI == EPI_RESF32) {
                    outf[idx] = v + res[idx];
                } else if constexpr (EPI == EPI_PART) {
                    outb[idx + (size_t)kz * M * N] = f2bf(v);
                } else {
                    outb[idx] = f2bf(v);
                }
            }
        }
    }
}

// ---------- FFN2 reduce: out = bf16(p0) + bf16(p1) + bias + residual ----------
__global__ void ffn2_reduce(const u16* __restrict__ p,
                            const float* __restrict__ b2,
                            const float* __restrict__ x2,
                            float* __restrict__ out)
{
    size_t i = ((size_t)blockIdx.x * 256 + threadIdx.x) * 4;
    U16x4 a0 = *reinterpret_cast<const U16x4*>(p + i);
    U16x4 a1 = *reinterpret_cast<const U16x4*>(p + (size_t)ROWS * D_MODEL + i);
    float4 r  = *reinterpret_cast<const float4*>(x2 + i);
    float4 bb = *reinterpret_cast<const float4*>(b2 + (i & (D_MODEL - 1)));
    float4 o;
    o.x = bf2f(a0.x) + bf2f(a1.x) + r.x + bb.x;
    o.y = bf2f(a0.y) + bf2f(a1.y) + r.y + bb.y;
    o.z = bf2f(a0.z) + bf2f(a1.z) + r.z + bb.z;
    o.w = bf2f(a0.w) + bf2f(a1.w) + r.w + bb.w;
    *reinterpret_cast<float4*>(out + i) = o;
}

// ---------- V transpose via LDS (coalesced both sides) ----------
__global__ __launch_bounds__(256) void vtrans(
    const u16* __restrict__ QKV, u16* __restrict__ VT)
{
    __shared__ u16 tile[64][72];
    const int st = blockIdx.x * 64;
    const int bh = blockIdx.y;
    const int b = bh >> 4, h = bh & 15;
    const int t = threadIdx.x;

    #pragma unroll
    for (int c = 0; c < 2; ++c) {
        int tok = c * 32 + (t >> 3);
        int d0 = (t & 7) * 8;
        bf16x8 v = ldg8(QKV + ((size_t)(b * SEQ + st + tok)) * QKVS + 2048 + h * HD + d0);
        *reinterpret_cast<bf16x8*>(&tile[tok][d0]) = v;
    }
    __syncthreads();
    u16* dst = VT + (size_t)bh * HD * SEQ + st;
    #pragma unroll
    for (int c = 0; c < 2; ++c) {
        int d = c * 32 + (t >> 3);
        int tok0 = (t & 7) * 8;
        u16 vals[8];
        #pragma unroll
        for (int i = 0; i < 8; ++i) vals[i] = tile[tok0 + i][d];
        *reinterpret_cast<bf16x8*>(dst + (size_t)d * SEQ + tok0) =
            *reinterpret_cast<const bf16x8*>(vals);
    }
}

// ---------- causal flash attention v8: 1 barrier/tile, K 3-buf / V 2-buf ----------
#define QBLK  64
#define KVBLK 64

__global__ __launch_bounds__(256, 3) void attn8(
    const u16* __restrict__ QKV, const u16* __restrict__ VT,
    u16* __restrict__ O)
{
    __shared__ u16 Ks[3][64 * 64];    // [kv][d], swizzle key (kv>>2)&7
    __shared__ u16 Vs[2][64 * 64];    // [d][kv], swizzle key d&7
    __shared__ u16 Pl[4][16 * 72];    // per-wave P[q][kv], stride 72

    const int i  = blockIdx.x;            // 0..15
    const int bh = blockIdx.y;
    const int b = bh >> 4, h = bh & 15;
    const int qta = 31 - i;               // heavy q-tile
    const int qtb = i;                    // light q-tile
    const int q0a = qta * QBLK, q0b = qtb * QBLK;
    const int t = threadIdx.x;
    const int lane = t & 63, w = t >> 6;
    const int lr = lane & 15, lg = lane >> 4;

    const size_t rowbase = (size_t)b * SEQ;
    const u16* Qg = QKV + rowbase * QKVS + h * HD;
    const u16* Kg = Qg + 1024;
    const u16* Vg = VT + (size_t)bh * HD * SEQ;

    const u16* qpa = Qg + (size_t)(q0a + w * 16 + lr) * QKVS;
    const u16* qpb = Qg + (size_t)(q0b + w * 16 + lr) * QKVS;
    bf16x8 qa0 = ldg8(qpa + lg * 8), qa1 = ldg8(qpa + 32 + lg * 8);
    bf16x8 qb0 = ldg8(qpb + lg * 8), qb1 = ldg8(qpb + 32 + lg * 8);

    f32x4 oa[4] = {}, ob[4] = {};
    float lsa[4] = {}, lsb[4] = {};

    const int ntiles = qta + 1;           // 17..32 (>= 3 always)
    u16* Pw = Pl[w];
    const float SC = 0.125f * 1.44269504089f;

    auto stageK = [&](int buf, int tt) {
        const int kv0 = tt * KVBLK;
        #pragma unroll
        for (int c = 0; c < 2; ++c) {
            int f = c * 256 + t;
            int row = f >> 3, slot = f & 7;
            int sgk = slot ^ ((row >> 2) & 7);
            gld_lds16(Kg + (size_t)(kv0 + row) * QKVS + sgk * 8, Ks[buf] + f * 8);
        }
    };
    auto stageV = [&](int buf, int tt) {
        const int kv0 = tt * KVBLK;
        #pragma unroll
        for (int c = 0; c < 2; ++c) {
            int f = c * 256 + t;
            int row = f >> 3, slot = f & 7;
            int sgv = slot ^ (row & 7);
            gld_lds16(Vg + (size_t)row * SEQ + kv0 + sgv * 8, Vs[buf] + f * 8);
        }
    };

    auto qtile = [&](bf16x8 qf0, bf16x8 qf1, f32x4* o, float* ls,
                     int q0, int kv0, bool diag, const u16* kb, const u16* vb) {
        f32x4 s[4] = {};
        __builtin_amdgcn_s_setprio(1);
        #pragma unroll
        for (int ni = 0; ni < 4; ++ni) {
            int row = lr * 4 + ni;
            const u16* base = kb + row * 64;
            int key = (row >> 2) & 7;
            bf16x8 k0 = *reinterpret_cast<const bf16x8*>(base + ((0 + lg) ^ key) * 8);
            bf16x8 k1 = *reinterpret_cast<const bf16x8*>(base + ((4 + lg) ^ key) * 8);
            s[ni] = mfma16(qf0, k0, s[ni]);
            s[ni] = mfma16(qf1, k1, s[ni]);
        }
        __builtin_amdgcn_s_setprio(0);

        #pragma unroll
        for (int j = 0; j < 4; ++j) {
            int qi = q0 + w * 16 + lg * 4 + j;
            float p0 = __builtin_amdgcn_exp2f(s[0][j] * SC);
            float p1 = __builtin_amdgcn_exp2f(s[1][j] * SC);
            float p2 = __builtin_amdgcn_exp2f(s[2][j] * SC);
            float p3 = __builtin_amdgcn_exp2f(s[3][j] * SC);
            if (diag) {
                int kvb = kv0 + lr * 4;
                p0 = (kvb     <= qi) ? p0 : 0.f;
                p1 = (kvb + 1 <= qi) ? p1 : 0.f;
                p2 = (kvb + 2 <= qi) ? p2 : 0.f;
                p3 = (kvb + 3 <= qi) ? p3 : 0.f;
            }
            ls[j] += (p0 + p1) + (p2 + p3);
            uint2 pk = make_uint2(cvtpk_bf16(p0, p1), cvtpk_bf16(p2, p3));
            *reinterpret_cast<uint2*>(&Pw[(lg * 4 + j) * 72 + lr * 4]) = pk;
        }

        bf16x8 pa0 = *reinterpret_cast<const bf16x8*>(Pw + lr * 72 + lg * 8);
        bf16x8 pa1 = *reinterpret_cast<const bf16x8*>(Pw + lr * 72 + 32 + lg * 8);
        __builtin_amdgcn_s_setprio(1);
        #pragma unroll
        for (int ni = 0; ni < 4; ++ni) {
            int row = ni * 16 + lr;
            const u16* base = vb + row * 64;
            bf16x8 v0 = *reinterpret_cast<const bf16x8*>(base + ((0 + lg) ^ (row & 7)) * 8);
            bf16x8 v1 = *reinterpret_cast<const bf16x8*>(base + ((4 + lg) ^ (row & 7)) * 8);
            o[ni] = mfma16(pa0, v0, o[ni]);
            o[ni] = mfma16(pa1, v1, o[ni]);
        }
        __builtin_amdgcn_s_setprio(0);
    };

    // prologue: V(0), K(0), K(1) in flight (order matters for vmcnt FIFO)
    stageV(0, 0);
    stageK(0, 0);
    stageK(1, 1);

    for (int tt = 0; tt < ntiles; ++tt) {
        __builtin_amdgcn_s_barrier();       // iter tt-1 compute complete
        if (tt + 1 < ntiles) stageV((tt + 1) & 1, tt + 1);
        if (tt + 2 < ntiles) stageK((tt + 2) % 3, tt + 2);
        if (tt + 2 < ntiles)
            asm volatile("s_waitcnt vmcnt(6)" ::: "memory");  // K(tt),V(tt) done
        else if (tt + 1 < ntiles)
            asm volatile("s_waitcnt vmcnt(4)" ::: "memory");
        else
            asm volatile("s_waitcnt vmcnt(0)" ::: "memory");

        const int kv0 = tt * KVBLK;
        const u16* kb = Ks[tt % 3];
        const u16* vb = Vs[tt & 1];

        qtile(qa0, qa1, oa, lsa, q0a, kv0, tt == qta, kb, vb);
        if (tt <= qtb)
            qtile(qb0, qb1, ob, lsb, q0b, kv0, tt == qtb, kb, vb);
    }

    #pragma unroll
    for (int j = 0; j < 4; ++j) {
        float va = lsa[j], vb2 = lsb[j];
        va += __shfl_xor(va, 1); vb2 += __shfl_xor(vb2, 1);
        va += __shfl_xor(va, 2); vb2 += __shfl_xor(vb2, 2);
        va += __shfl_xor(va, 4); vb2 += __shfl_xor(vb2, 4);
        va += __shfl_xor(va, 8); vb2 += __shfl_xor(vb2, 8);
        lsa[j] = va; lsb[j] = vb2;
    }

    u16* Oa = O + (rowbase + q0a + w * 16) * D_MODEL + h * HD;
    u16* Ob = O + (rowbase + q0b + w * 16) * D_MODEL + h * HD;
    #pragma unroll
    for (int j = 0; j < 4; ++j) {
        float inva = 1.0f / lsa[j];
        float invb = 1.0f / lsb[j];
        int r = (lg * 4 + j) * D_MODEL;
        #pragma unroll
        for (int ni = 0; ni < 4; ++ni) {
            Oa[r + ni * 16 + lr] = f2bf(oa[ni][j] * inva);
            Ob[r + ni * 16 + lr] = f2bf(ob[ni][j] * invb);
        }
    }
}

// ---------- launch ----------
extern "C" void kernel_launch(void* const* d_in, const int* in_sizes, int n_in,
                              void* d_out, int out_size, void* d_ws, size_t ws_size,
                              hipStream_t stream)
{
    (void)in_sizes; (void)n_in; (void)out_size; (void)ws_size;
    const float* x   = (const float*)d_in[0];
    const float* Wq  = (const float*)d_in[2];
    const float* bq  = (const float*)d_in[3];
    const float* Wk  = (const float*)d_in[4];
    const float* bk  = (const float*)d_in[5];
    const float* Wv  = (const float*)d_in[6];
    const float* bv  = (const float*)d_in[7];
    const float* Wo  = (const float*)d_in[8];
    const float* bo  = (const float*)d_in[9];
    const float* g1  = (const float*)d_in[10];
    const float* be1 = (const float*)d_in[11];
    const float* g2  = (const float*)d_in[12];
    const float* be2 = (const float*)d_in[13];
    const float* W1  = (const float*)d_in[14];
    const float* b1  = (const float*)d_in[15];
    const float* W2  = (const float*)d_in[16];
    const float* b2  = (const float*)d_in[17];
    float* out = (float*)d_out;

    const size_t MM = 1 << 20;   // 1M elems
    u16* Wqkv_b = (u16*)d_ws;            // 3M u16 (Wq,Wk,Wv packed [3072][1024])
    u16* Wo_b = Wqkv_b + 3 * MM;
    u16* W1_b = Wo_b + MM;               // 4M
    u16* W2_b = W1_b + 4 * MM;           // 4M
    u16* hbuf = W2_b + 4 * MM;           // 4M (LN out; dead after its GEMM)
    u16* QKVb = hbuf + 4 * MM;           // 12M  [4096][3072]
    u16* ctx  = QKVb + 12 * MM;          // 4M
    u16* ffn1 = ctx + 4 * MM;            // 16M
    float* x2 = (float*)(ffn1 + 16 * MM);        // 4M f32
    float* bqkv = (float*)(x2 + 4 * MM);         // 3072 f32
    u16* VTb = hbuf;                     // aliases hbuf (dead after QKV GEMM)
    u16* fpart = QKVb;                   // FFN2 bf16 partials alias QKV (dead)

    // fused prep: weight cvt + LN1 + bias pack (one launch)
    prep<<<12288 + ROWS + 3, 256, 0, stream>>>(Wq, Wk, Wv, Wo, W1, W2, Wqkv_b,
                                               x, g1, be1, hbuf, bq, bk, bv, bqkv);

    // fused QKV projection: m97 single-buffer, row-major grid (32, 24)
    dim3 gqkv(ROWS / 128, QKVS / 128);
    gemm97<EPI_BF16><<<gqkv, 256, 0, stream>>>(hbuf, Wqkv_b, bqkv, nullptr,
                                               QKVb, nullptr, ROWS, QKVS, 1024, 1024);

    // V transpose (hbuf dead now)
    vtrans<<<dim3(SEQ / 64, BATCH * NH), 256, 0, stream>>>(QKVb, VTb);

    // attention: paired q-tiles, 1-barrier pipeline, 512 equal blocks
    dim3 ga(SEQ / QBLK / 2, BATCH * NH);      // (16, 32)
    attn8<<<ga, 256, 0, stream>>>(QKVb, VTb, ctx);

    // Wo projection + residual (row-major grid (32, 8))
    dim3 gq(ROWS / 128, D_MODEL / 128);
    gemm_bt<EPI_RESF32, 1><<<gq, 256, 0, stream>>>(ctx, Wo_b, bo, x, nullptr, x2,
                                                   ROWS, D_MODEL, 1024, 1024);

    // LN2
    ln_bf16<<<ROWS, 256, 0, stream>>>(x2, g2, be2, hbuf);

    // FFN1 + GELU: m97 single-buffer, row-major grid (32, 32)
    dim3 gf1(ROWS / 128, D_FF / 128);
    gemm97<EPI_GELU><<<gf1, 256, 0, stream>>>(hbuf, W1_b, b1, nullptr, ffn1, nullptr,
                                              ROWS, D_FF, 1024, 1024);

    // FFN2 split-K2: col-major grid, bf16 partials; reduce adds bias+residual
    dim3 gf2(D_MODEL / 128, ROWS / 128, 2);
    gemm_bt<EPI_PART, 0><<<gf2, 256, 0, stream>>>(ffn1, W2_b, nullptr, nullptr,
                                                  fpart, nullptr, ROWS, D_MODEL, 2048, 4096);
    ffn2_reduce<<<(ROWS * D_MODEL) / 1024, 256, 0, stream>>>(fpart, b2, x2, out);
}

// Round 18
// 223.495 us; speedup vs baseline: 1.8769x; 1.8769x over previous
//
#include <hip/hip_runtime.h>
#include <hip/hip_bf16.h>
#include <cstdint>
#include <cstddef>

typedef unsigned short u16;
typedef __bf16 bf16x8 __attribute__((ext_vector_type(8)));
typedef float f32x4 __attribute__((ext_vector_type(4)));

#define D_MODEL 1024
#define D_FF    4096
#define BATCH   2
#define SEQ     2048
#define NH      16
#define HD      64
#define ROWS    (BATCH*SEQ)   // 4096
#define QKVS    3072          // packed QKV row stride

// ---------- helpers ----------
__device__ __forceinline__ u16 f2bf(float f) {
    union { float f; uint32_t u; } v; v.f = f;
    uint32_t u = v.u;
    u += 0x7FFF + ((u >> 16) & 1);   // RNE
    return (u16)(u >> 16);
}

__device__ __forceinline__ float bf2f(u16 u) {
    union { uint32_t u; float f; } v; v.u = (uint32_t)u << 16;
    return v.f;
}

__device__ __forceinline__ uint32_t cvtpk_bf16(float lo, float hi) {
    uint32_t r;
    asm("v_cvt_pk_bf16_f32 %0, %1, %2" : "=v"(r) : "v"(lo), "v"(hi));
    return r;
}

__device__ __forceinline__ bf16x8 ldg8(const u16* p) {
    return *reinterpret_cast<const bf16x8*>(p);
}

__device__ __forceinline__ f32x4 mfma16(bf16x8 a, bf16x8 b, f32x4 c) {
    return __builtin_amdgcn_mfma_f32_16x16x32_bf16(a, b, c, 0, 0, 0);
}

__device__ __forceinline__ void gld_lds16(const void* g, void* l) {
    __builtin_amdgcn_global_load_lds(
        (const __attribute__((address_space(1))) void*)g,
        (__attribute__((address_space(3))) void*)l, 16, 0, 0);
}

// GELU, tanh-form via exp2; |err| <= ~3e-3.
__device__ __forceinline__ float gelu_f(float x) {
    float u = fmaf(0.044715f * x, x * x, x);
    float z = fminf(-2.3022036f * u, 126.0f);
    float e = __builtin_amdgcn_exp2f(z);
    return x / (1.0f + e);
}

struct alignas(8) U16x4 { u16 x, y, z, w; };

// ---------- fused prep: weight cvt (12288 blk) + LN1 (4096 blk) + bias pack (3 blk) ----------
__global__ __launch_bounds__(256) void prep(
    const float* __restrict__ s0, const float* __restrict__ s1,
    const float* __restrict__ s2, const float* __restrict__ s3,
    const float* __restrict__ s4, const float* __restrict__ s5,
    u16* __restrict__ wout,
    const float* __restrict__ x, const float* __restrict__ g1,
    const float* __restrict__ be1, u16* __restrict__ hbuf,
    const float* __restrict__ bq, const float* __restrict__ bk,
    const float* __restrict__ bv, float* __restrict__ bqkv)
{
    const size_t MM1 = 1 << 20;
    const int bid = blockIdx.x;
    const int t = threadIdx.x;

    if (bid < 12288) {
        // weight f32 -> bf16
        size_t i = (size_t)bid * 1024 + t * 4;
        const float* src; size_t off;
        if      (i <     MM1) { src = s0; off = i; }
        else if (i < 2 * MM1) { src = s1; off = i - MM1; }
        else if (i < 3 * MM1) { src = s2; off = i - 2 * MM1; }
        else if (i < 4 * MM1) { src = s3; off = i - 3 * MM1; }
        else if (i < 8 * MM1) { src = s4; off = i - 4 * MM1; }
        else                  { src = s5; off = i - 8 * MM1; }
        float4 f = *reinterpret_cast<const float4*>(src + off);
        U16x4 o{ f2bf(f.x), f2bf(f.y), f2bf(f.z), f2bf(f.w) };
        *reinterpret_cast<U16x4*>(wout + i) = o;
    } else if (bid < 12288 + ROWS) {
        // LayerNorm 1
        int row = bid - 12288;
        const float* xr = x + (size_t)row * D_MODEL;
        float4 v = *reinterpret_cast<const float4*>(xr + t * 4);
        float s = v.x + v.y + v.z + v.w;
        float q = v.x*v.x + v.y*v.y + v.z*v.z + v.w*v.w;
        #pragma unroll
        for (int off = 1; off < 64; off <<= 1) {
            s += __shfl_xor(s, off);
            q += __shfl_xor(q, off);
        }
        __shared__ float red[8];
        if ((t & 63) == 0) { red[(t >> 6) * 2] = s; red[(t >> 6) * 2 + 1] = q; }
        __syncthreads();
        float sum = red[0] + red[2] + red[4] + red[6];
        float sq  = red[1] + red[3] + red[5] + red[7];
        float mu  = sum * (1.0f / D_MODEL);
        float var = sq * (1.0f / D_MODEL) - mu * mu;
        float rstd = rsqrtf(var + 1e-6f);
        float4 gg = *reinterpret_cast<const float4*>(g1 + t * 4);
        float4 bb = *reinterpret_cast<const float4*>(be1 + t * 4);
        U16x4 o{ f2bf((v.x - mu) * rstd * gg.x + bb.x),
                 f2bf((v.y - mu) * rstd * gg.y + bb.y),
                 f2bf((v.z - mu) * rstd * gg.z + bb.z),
                 f2bf((v.w - mu) * rstd * gg.w + bb.w) };
        *reinterpret_cast<U16x4*>(hbuf + (size_t)row * D_MODEL + t * 4) = o;
    } else {
        // pack QKV bias: 3 blocks x 1024 floats
        int j = bid - (12288 + ROWS);
        const float* src = (j == 0) ? bq : (j == 1) ? bk : bv;
        float4 f = *reinterpret_cast<const float4*>(src + t * 4);
        *reinterpret_cast<float4*>(bqkv + j * 1024 + t * 4) = f;
    }
}

// ---------- LayerNorm (f32 in, bf16 out) ----------
__global__ __launch_bounds__(256) void ln_bf16(
    const float* __restrict__ x, const float* __restrict__ g,
    const float* __restrict__ b, u16* __restrict__ out)
{
    int row = blockIdx.x;
    const float* xr = x + (size_t)row * D_MODEL;
    int t = threadIdx.x;
    float4 v = *reinterpret_cast<const float4*>(xr + t * 4);
    float s = v.x + v.y + v.z + v.w;
    float q = v.x*v.x + v.y*v.y + v.z*v.z + v.w*v.w;
    #pragma unroll
    for (int off = 1; off < 64; off <<= 1) {
        s += __shfl_xor(s, off);
        q += __shfl_xor(q, off);
    }
    __shared__ float red[8];
    if ((t & 63) == 0) { red[(t >> 6) * 2] = s; red[(t >> 6) * 2 + 1] = q; }
    __syncthreads();
    float sum = red[0] + red[2] + red[4] + red[6];
    float sq  = red[1] + red[3] + red[5] + red[7];
    float mu  = sum * (1.0f / D_MODEL);
    float var = sq * (1.0f / D_MODEL) - mu * mu;
    float rstd = rsqrtf(var + 1e-6f);
    float4 gg = *reinterpret_cast<const float4*>(g + t * 4);
    float4 bb = *reinterpret_cast<const float4*>(b + t * 4);
    U16x4 o{ f2bf((v.x - mu) * rstd * gg.x + bb.x),
             f2bf((v.y - mu) * rstd * gg.y + bb.y),
             f2bf((v.z - mu) * rstd * gg.z + bb.z),
             f2bf((v.w - mu) * rstd * gg.w + bb.w) };
    *reinterpret_cast<U16x4*>(out + (size_t)row * D_MODEL + t * 4) = o;
}

#define EPI_BF16   0
#define EPI_RESF32 1
#define EPI_GELU   2
#define EPI_PART   3

// ---------- GEMM 128x128, m97-style single-buffer, 4 blocks/CU ----------
// NOTE: bounds (256,4) -> VGPR 64, no spill. (256,5) spilled acc to scratch
// (VGPR 48, 420 MB scratch writes, 4x slowdown) -- do not raise.
template<int EPI>
__global__ __launch_bounds__(256, 4) void gemm97(
    const u16* __restrict__ A, const u16* __restrict__ B,
    const float* __restrict__ bias, const float* __restrict__ res,
    u16* __restrict__ outb, float* __restrict__ outf,
    int M, int N, int K, int KS)
{
    __shared__ u16 As[128 * 64];
    __shared__ u16 Bs[128 * 64];
    const int t = threadIdx.x;
    const int lane = t & 63, w = t >> 6;
    const int lr = lane & 15, lg = lane >> 4;
    const int wrr = (w >> 1) * 64, wcc = (w & 1) * 64;
    const int brow = blockIdx.x * 128, bcol = blockIdx.y * 128;   // row-major
    const u16* Ag = A + (size_t)brow * KS;
    const u16* Bg = B + (size_t)bcol * KS;

    f32x4 acc[4][4] = {};
    const int NT = K >> 6;

    for (int kt = 0; kt < NT; ++kt) {
        #pragma unroll
        for (int c = 0; c < 4; ++c) {
            int f = c * 256 + t;
            int row = f >> 3, slot = f & 7;
            int sg = slot ^ (row & 7);
            gld_lds16(Ag + (size_t)row * KS + kt * 64 + sg * 8, As + f * 8);
            gld_lds16(Bg + (size_t)row * KS + kt * 64 + sg * 8, Bs + f * 8);
        }
        __syncthreads();

        bf16x8 af[4][2];
        #pragma unroll
        for (int mi = 0; mi < 4; ++mi) {
            int row = wrr + mi * 16 + lr;
            const u16* bp = As + row * 64;
            int key = row & 7;
            af[mi][0] = ldg8(bp + ((0 + lg) ^ key) * 8);
            af[mi][1] = ldg8(bp + ((4 + lg) ^ key) * 8);
        }
        __builtin_amdgcn_s_setprio(1);
        #pragma unroll
        for (int ni = 0; ni < 4; ++ni) {
            int row = wcc + ni * 16 + lr;
            const u16* bp = Bs + row * 64;
            int key = row & 7;
            bf16x8 b0 = ldg8(bp + ((0 + lg) ^ key) * 8);
            bf16x8 b1 = ldg8(bp + ((4 + lg) ^ key) * 8);
            #pragma unroll
            for (int mi = 0; mi < 4; ++mi) {
                acc[mi][ni] = mfma16(af[mi][0], b0, acc[mi][ni]);
                acc[mi][ni] = mfma16(af[mi][1], b1, acc[mi][ni]);
            }
        }
        __builtin_amdgcn_s_setprio(0);
        __syncthreads();
    }

    #pragma unroll
    for (int mi = 0; mi < 4; ++mi) {
        int r0 = brow + wrr + mi * 16 + lg * 4;
        #pragma unroll
        for (int ni = 0; ni < 4; ++ni) {
            int c = bcol + wcc + ni * 16 + lr;
            float bv = bias[c];
            #pragma unroll
            for (int j = 0; j < 4; ++j) {
                float v = acc[mi][ni][j] + bv;
                size_t idx = (size_t)(r0 + j) * N + c;
                if constexpr (EPI == EPI_GELU) {
                    outb[idx] = f2bf(gelu_f(v));
                } else if constexpr (EPI == EPI_RESF32) {
                    outf[idx] = v + res[idx];
                } else {
                    outb[idx] = f2bf(v);
                }
            }
        }
    }
}

// ---------- GEMM 128x128, 2-deep counted-vmcnt ----------
// RM=1: row-grouping. RM=0: col-grouping (FFN2: B L2-resident, stream A).
// EPI_PART: writes bf16 partial at outb + kz*M*N.
template<int EPI, int RM>
__global__ __launch_bounds__(256, 2) void gemm_bt(
    const u16* __restrict__ A, const u16* __restrict__ B,
    const float* __restrict__ bias, const float* __restrict__ res,
    u16* __restrict__ outb, float* __restrict__ outf,
    int M, int N, int K, int KS)
{
    __shared__ u16 As[2][128 * 64];
    __shared__ u16 Bs[2][128 * 64];
    const int t = threadIdx.x;
    const int lane = t & 63;
    const int w = t >> 6;
    const int lr = lane & 15, lg = lane >> 4;
    const int wrr = (w >> 1) * 64, wcc = (w & 1) * 64;
    const int brow = (RM ? blockIdx.x : blockIdx.y) * 128;
    const int bcol = (RM ? blockIdx.y : blockIdx.x) * 128;
    const int kz = blockIdx.z;
    const u16* Ag = A + (size_t)brow * KS + (size_t)kz * K;
    const u16* Bg = B + (size_t)bcol * KS + (size_t)kz * K;

    f32x4 acc[4][4] = {};

    const int NT = K >> 6;

    auto stage = [&](int buf, int kt) {
        const u16* ga = Ag + kt * 64;
        const u16* gb = Bg + kt * 64;
        u16* la = As[buf];
        u16* lb = Bs[buf];
        #pragma unroll
        for (int c = 0; c < 4; ++c) {
            int f = c * 256 + t;
            int row = f >> 3, slot = f & 7;
            int sg = slot ^ (row & 7);
            gld_lds16(ga + (size_t)row * KS + sg * 8, la + f * 8);
            gld_lds16(gb + (size_t)row * KS + sg * 8, lb + f * 8);
        }
    };

    auto compute = [&](int buf) {
        const u16* la = As[buf];
        const u16* lb = Bs[buf];
        bf16x8 af[4][2];
        #pragma unroll
        for (int mi = 0; mi < 4; ++mi) {
            int row = wrr + mi * 16 + lr;
            int base = row * 64;
            af[mi][0] = *reinterpret_cast<const bf16x8*>(la + base + ((0 + lg) ^ (row & 7)) * 8);
            af[mi][1] = *reinterpret_cast<const bf16x8*>(la + base + ((4 + lg) ^ (row & 7)) * 8);
        }
        __builtin_amdgcn_s_setprio(1);
        #pragma unroll
        for (int ni = 0; ni < 4; ++ni) {
            int row = wcc + ni * 16 + lr;
            int base = row * 64;
            bf16x8 b0 = *reinterpret_cast<const bf16x8*>(lb + base + ((0 + lg) ^ (row & 7)) * 8);
            bf16x8 b1 = *reinterpret_cast<const bf16x8*>(lb + base + ((4 + lg) ^ (row & 7)) * 8);
            #pragma unroll
            for (int mi = 0; mi < 4; ++mi) {
                acc[mi][ni] = mfma16(af[mi][0], b0, acc[mi][ni]);
                acc[mi][ni] = mfma16(af[mi][1], b1, acc[mi][ni]);
            }
        }
        __builtin_amdgcn_s_setprio(0);
    };

    stage(0, 0);
    if (NT > 1) {
        stage(1, 1);
        asm volatile("s_waitcnt vmcnt(8)" ::: "memory");
    } else {
        asm volatile("s_waitcnt vmcnt(0)" ::: "memory");
    }
    __builtin_amdgcn_s_barrier();

    for (int kt = 0; kt < NT; ++kt) {
        compute(kt & 1);
        if (kt + 1 == NT) break;
        __builtin_amdgcn_s_barrier();
        if (kt + 2 < NT) {
            stage(kt & 1, kt + 2);
            asm volatile("s_waitcnt vmcnt(8)" ::: "memory");
        } else {
            asm volatile("s_waitcnt vmcnt(0)" ::: "memory");
        }
        __builtin_amdgcn_s_barrier();
    }

    #pragma unroll
    for (int mi = 0; mi < 4; ++mi) {
        int r0 = brow + wrr + mi * 16 + lg * 4;
        #pragma unroll
        for (int ni = 0; ni < 4; ++ni) {
            int c = bcol + wcc + ni * 16 + lr;
            float bv = 0.f;
            if constexpr (EPI != EPI_PART) bv = bias[c];
            #pragma unroll
            for (int j = 0; j < 4; ++j) {
                float v = acc[mi][ni][j] + bv;
                size_t idx = (size_t)(r0 + j) * N + c;
                if constexpr (EPI == EPI_GELU) {
                    outb[idx] = f2bf(gelu_f(v));
                } else if constexpr (EPI == EPI_RESF32) {
                    outf[idx] = v + res[idx];
                } else if constexpr (EPI == EPI_PART) {
                    outb[idx + (size_t)kz * M * N] = f2bf(v);
                } else {
                    outb[idx] = f2bf(v);
                }
            }
        }
    }
}

// ---------- FFN2 reduce: out = bf16(p0) + bf16(p1) + bias + residual ----------
__global__ void ffn2_reduce(const u16* __restrict__ p,
                            const float* __restrict__ b2,
                            const float* __restrict__ x2,
                            float* __restrict__ out)
{
    size_t i = ((size_t)blockIdx.x * 256 + threadIdx.x) * 4;
    U16x4 a0 = *reinterpret_cast<const U16x4*>(p + i);
    U16x4 a1 = *reinterpret_cast<const U16x4*>(p + (size_t)ROWS * D_MODEL + i);
    float4 r  = *reinterpret_cast<const float4*>(x2 + i);
    float4 bb = *reinterpret_cast<const float4*>(b2 + (i & (D_MODEL - 1)));
    float4 o;
    o.x = bf2f(a0.x) + bf2f(a1.x) + r.x + bb.x;
    o.y = bf2f(a0.y) + bf2f(a1.y) + r.y + bb.y;
    o.z = bf2f(a0.z) + bf2f(a1.z) + r.z + bb.z;
    o.w = bf2f(a0.w) + bf2f(a1.w) + r.w + bb.w;
    *reinterpret_cast<float4*>(out + i) = o;
}

// ---------- V transpose via LDS (coalesced both sides) ----------
__global__ __launch_bounds__(256) void vtrans(
    const u16* __restrict__ QKV, u16* __restrict__ VT)
{
    __shared__ u16 tile[64][72];
    const int st = blockIdx.x * 64;
    const int bh = blockIdx.y;
    const int b = bh >> 4, h = bh & 15;
    const int t = threadIdx.x;

    #pragma unroll
    for (int c = 0; c < 2; ++c) {
        int tok = c * 32 + (t >> 3);
        int d0 = (t & 7) * 8;
        bf16x8 v = ldg8(QKV + ((size_t)(b * SEQ + st + tok)) * QKVS + 2048 + h * HD + d0);
        *reinterpret_cast<bf16x8*>(&tile[tok][d0]) = v;
    }
    __syncthreads();
    u16* dst = VT + (size_t)bh * HD * SEQ + st;
    #pragma unroll
    for (int c = 0; c < 2; ++c) {
        int d = c * 32 + (t >> 3);
        int tok0 = (t & 7) * 8;
        u16 vals[8];
        #pragma unroll
        for (int i = 0; i < 8; ++i) vals[i] = tile[tok0 + i][d];
        *reinterpret_cast<bf16x8*>(dst + (size_t)d * SEQ + tok0) =
            *reinterpret_cast<const bf16x8*>(vals);
    }
}

// ---------- causal flash attention v8: 1 barrier/tile, K 3-buf / V 2-buf ----------
#define QBLK  64
#define KVBLK 64

__global__ __launch_bounds__(256, 3) void attn8(
    const u16* __restrict__ QKV, const u16* __restrict__ VT,
    u16* __restrict__ O)
{
    __shared__ u16 Ks[3][64 * 64];    // [kv][d], swizzle key (kv>>2)&7
    __shared__ u16 Vs[2][64 * 64];    // [d][kv], swizzle key d&7
    __shared__ u16 Pl[4][16 * 72];    // per-wave P[q][kv], stride 72

    const int i  = blockIdx.x;            // 0..15
    const int bh = blockIdx.y;
    const int b = bh >> 4, h = bh & 15;
    const int qta = 31 - i;               // heavy q-tile
    const int qtb = i;                    // light q-tile
    const int q0a = qta * QBLK, q0b = qtb * QBLK;
    const int t = threadIdx.x;
    const int lane = t & 63, w = t >> 6;
    const int lr = lane & 15, lg = lane >> 4;

    const size_t rowbase = (size_t)b * SEQ;
    const u16* Qg = QKV + rowbase * QKVS + h * HD;
    const u16* Kg = Qg + 1024;
    const u16* Vg = VT + (size_t)bh * HD * SEQ;

    const u16* qpa = Qg + (size_t)(q0a + w * 16 + lr) * QKVS;
    const u16* qpb = Qg + (size_t)(q0b + w * 16 + lr) * QKVS;
    bf16x8 qa0 = ldg8(qpa + lg * 8), qa1 = ldg8(qpa + 32 + lg * 8);
    bf16x8 qb0 = ldg8(qpb + lg * 8), qb1 = ldg8(qpb + 32 + lg * 8);

    f32x4 oa[4] = {}, ob[4] = {};
    float lsa[4] = {}, lsb[4] = {};

    const int ntiles = qta + 1;           // 17..32 (>= 3 always)
    u16* Pw = Pl[w];
    const float SC = 0.125f * 1.44269504089f;

    auto stageK = [&](int buf, int tt) {
        const int kv0 = tt * KVBLK;
        #pragma unroll
        for (int c = 0; c < 2; ++c) {
            int f = c * 256 + t;
            int row = f >> 3, slot = f & 7;
            int sgk = slot ^ ((row >> 2) & 7);
            gld_lds16(Kg + (size_t)(kv0 + row) * QKVS + sgk * 8, Ks[buf] + f * 8);
        }
    };
    auto stageV = [&](int buf, int tt) {
        const int kv0 = tt * KVBLK;
        #pragma unroll
        for (int c = 0; c < 2; ++c) {
            int f = c * 256 + t;
            int row = f >> 3, slot = f & 7;
            int sgv = slot ^ (row & 7);
            gld_lds16(Vg + (size_t)row * SEQ + kv0 + sgv * 8, Vs[buf] + f * 8);
        }
    };

    auto qtile = [&](bf16x8 qf0, bf16x8 qf1, f32x4* o, float* ls,
                     int q0, int kv0, bool diag, const u16* kb, const u16* vb) {
        f32x4 s[4] = {};
        __builtin_amdgcn_s_setprio(1);
        #pragma unroll
        for (int ni = 0; ni < 4; ++ni) {
            int row = lr * 4 + ni;
            const u16* base = kb + row * 64;
            int key = (row >> 2) & 7;
            bf16x8 k0 = *reinterpret_cast<const bf16x8*>(base + ((0 + lg) ^ key) * 8);
            bf16x8 k1 = *reinterpret_cast<const bf16x8*>(base + ((4 + lg) ^ key) * 8);
            s[ni] = mfma16(qf0, k0, s[ni]);
            s[ni] = mfma16(qf1, k1, s[ni]);
        }
        __builtin_amdgcn_s_setprio(0);

        #pragma unroll
        for (int j = 0; j < 4; ++j) {
            int qi = q0 + w * 16 + lg * 4 + j;
            float p0 = __builtin_amdgcn_exp2f(s[0][j] * SC);
            float p1 = __builtin_amdgcn_exp2f(s[1][j] * SC);
            float p2 = __builtin_amdgcn_exp2f(s[2][j] * SC);
            float p3 = __builtin_amdgcn_exp2f(s[3][j] * SC);
            if (diag) {
                int kvb = kv0 + lr * 4;
                p0 = (kvb     <= qi) ? p0 : 0.f;
                p1 = (kvb + 1 <= qi) ? p1 : 0.f;
                p2 = (kvb + 2 <= qi) ? p2 : 0.f;
                p3 = (kvb + 3 <= qi) ? p3 : 0.f;
            }
            ls[j] += (p0 + p1) + (p2 + p3);
            uint2 pk = make_uint2(cvtpk_bf16(p0, p1), cvtpk_bf16(p2, p3));
            *reinterpret_cast<uint2*>(&Pw[(lg * 4 + j) * 72 + lr * 4]) = pk;
        }

        bf16x8 pa0 = *reinterpret_cast<const bf16x8*>(Pw + lr * 72 + lg * 8);
        bf16x8 pa1 = *reinterpret_cast<const bf16x8*>(Pw + lr * 72 + 32 + lg * 8);
        __builtin_amdgcn_s_setprio(1);
        #pragma unroll
        for (int ni = 0; ni < 4; ++ni) {
            int row = ni * 16 + lr;
            const u16* base = vb + row * 64;
            bf16x8 v0 = *reinterpret_cast<const bf16x8*>(base + ((0 + lg) ^ (row & 7)) * 8);
            bf16x8 v1 = *reinterpret_cast<const bf16x8*>(base + ((4 + lg) ^ (row & 7)) * 8);
            o[ni] = mfma16(pa0, v0, o[ni]);
            o[ni] = mfma16(pa1, v1, o[ni]);
        }
        __builtin_amdgcn_s_setprio(0);
    };

    // prologue: V(0), K(0), K(1) in flight (order matters for vmcnt FIFO)
    stageV(0, 0);
    stageK(0, 0);
    stageK(1, 1);

    for (int tt = 0; tt < ntiles; ++tt) {
        __builtin_amdgcn_s_barrier();       // iter tt-1 compute complete
        if (tt + 1 < ntiles) stageV((tt + 1) & 1, tt + 1);
        if (tt + 2 < ntiles) stageK((tt + 2) % 3, tt + 2);
        if (tt + 2 < ntiles)
            asm volatile("s_waitcnt vmcnt(6)" ::: "memory");  // K(tt),V(tt) done
        else if (tt + 1 < ntiles)
            asm volatile("s_waitcnt vmcnt(4)" ::: "memory");
        else
            asm volatile("s_waitcnt vmcnt(0)" ::: "memory");

        const int kv0 = tt * KVBLK;
        const u16* kb = Ks[tt % 3];
        const u16* vb = Vs[tt & 1];

        qtile(qa0, qa1, oa, lsa, q0a, kv0, tt == qta, kb, vb);
        if (tt <= qtb)
            qtile(qb0, qb1, ob, lsb, q0b, kv0, tt == qtb, kb, vb);
    }

    #pragma unroll
    for (int j = 0; j < 4; ++j) {
        float va = lsa[j], vb2 = lsb[j];
        va += __shfl_xor(va, 1); vb2 += __shfl_xor(vb2, 1);
        va += __shfl_xor(va, 2); vb2 += __shfl_xor(vb2, 2);
        va += __shfl_xor(va, 4); vb2 += __shfl_xor(vb2, 4);
        va += __shfl_xor(va, 8); vb2 += __shfl_xor(vb2, 8);
        lsa[j] = va; lsb[j] = vb2;
    }

    u16* Oa = O + (rowbase + q0a + w * 16) * D_MODEL + h * HD;
    u16* Ob = O + (rowbase + q0b + w * 16) * D_MODEL + h * HD;
    #pragma unroll
    for (int j = 0; j < 4; ++j) {
        float inva = 1.0f / lsa[j];
        float invb = 1.0f / lsb[j];
        int r = (lg * 4 + j) * D_MODEL;
        #pragma unroll
        for (int ni = 0; ni < 4; ++ni) {
            Oa[r + ni * 16 + lr] = f2bf(oa[ni][j] * inva);
            Ob[r + ni * 16 + lr] = f2bf(ob[ni][j] * invb);
        }
    }
}

// ---------- launch ----------
extern "C" void kernel_launch(void* const* d_in, const int* in_sizes, int n_in,
                              void* d_out, int out_size, void* d_ws, size_t ws_size,
                              hipStream_t stream)
{
    (void)in_sizes; (void)n_in; (void)out_size; (void)ws_size;
    const float* x   = (const float*)d_in[0];
    const float* Wq  = (const float*)d_in[2];
    const float* bq  = (const float*)d_in[3];
    const float* Wk  = (const float*)d_in[4];
    const float* bk  = (const float*)d_in[5];
    const float* Wv  = (const float*)d_in[6];
    const float* bv  = (const float*)d_in[7];
    const float* Wo  = (const float*)d_in[8];
    const float* bo  = (const float*)d_in[9];
    const float* g1  = (const float*)d_in[10];
    const float* be1 = (const float*)d_in[11];
    const float* g2  = (const float*)d_in[12];
    const float* be2 = (const float*)d_in[13];
    const float* W1  = (const float*)d_in[14];
    const float* b1  = (const float*)d_in[15];
    const float* W2  = (const float*)d_in[16];
    const float* b2  = (const float*)d_in[17];
    float* out = (float*)d_out;

    const size_t MM = 1 << 20;   // 1M elems
    u16* Wqkv_b = (u16*)d_ws;            // 3M u16 (Wq,Wk,Wv packed [3072][1024])
    u16* Wo_b = Wqkv_b + 3 * MM;
    u16* W1_b = Wo_b + MM;               // 4M
    u16* W2_b = W1_b + 4 * MM;           // 4M
    u16* hbuf = W2_b + 4 * MM;           // 4M (LN out; dead after its GEMM)
    u16* QKVb = hbuf + 4 * MM;           // 12M  [4096][3072]
    u16* ctx  = QKVb + 12 * MM;          // 4M
    u16* ffn1 = ctx + 4 * MM;            // 16M
    float* x2 = (float*)(ffn1 + 16 * MM);        // 4M f32
    float* bqkv = (float*)(x2 + 4 * MM);         // 3072 f32
    u16* VTb = hbuf;                     // aliases hbuf (dead after QKV GEMM)
    u16* fpart = QKVb;                   // FFN2 bf16 partials alias QKV (dead)

    // fused prep: weight cvt + LN1 + bias pack (one launch)
    prep<<<12288 + ROWS + 3, 256, 0, stream>>>(Wq, Wk, Wv, Wo, W1, W2, Wqkv_b,
                                               x, g1, be1, hbuf, bq, bk, bv, bqkv);

    // fused QKV projection: m97 single-buffer, row-major grid (32, 24)
    dim3 gqkv(ROWS / 128, QKVS / 128);
    gemm97<EPI_BF16><<<gqkv, 256, 0, stream>>>(hbuf, Wqkv_b, bqkv, nullptr,
                                               QKVb, nullptr, ROWS, QKVS, 1024, 1024);

    // V transpose (hbuf dead now)
    vtrans<<<dim3(SEQ / 64, BATCH * NH), 256, 0, stream>>>(QKVb, VTb);

    // attention: paired q-tiles, 1-barrier pipeline, 512 equal blocks
    dim3 ga(SEQ / QBLK / 2, BATCH * NH);      // (16, 32)
    attn8<<<ga, 256, 0, stream>>>(QKVb, VTb, ctx);

    // Wo projection + residual (row-major grid (32, 8))
    dim3 gq(ROWS / 128, D_MODEL / 128);
    gemm_bt<EPI_RESF32, 1><<<gq, 256, 0, stream>>>(ctx, Wo_b, bo, x, nullptr, x2,
                                                   ROWS, D_MODEL, 1024, 1024);

    // LN2
    ln_bf16<<<ROWS, 256, 0, stream>>>(x2, g2, be2, hbuf);

    // FFN1 + GELU: m97 single-buffer, row-major grid (32, 32)
    dim3 gf1(ROWS / 128, D_FF / 128);
    gemm97<EPI_GELU><<<gf1, 256, 0, stream>>>(hbuf, W1_b, b1, nullptr, ffn1, nullptr,
                                              ROWS, D_FF, 1024, 1024);

    // FFN2 split-K2: col-major grid, bf16 partials; reduce adds bias+residual
    dim3 gf2(D_MODEL / 128, ROWS / 128, 2);
    gemm_bt<EPI_PART, 0><<<gf2, 256, 0, stream>>>(ffn1, W2_b, nullptr, nullptr,
                                                  fpart, nullptr, ROWS, D_MODEL, 2048, 4096);
    ffn2_reduce<<<(ROWS * D_MODEL) / 1024, 256, 0, stream>>>(fpart, b2, x2, out);
}

// Round 19
// 215.220 us; speedup vs baseline: 1.9491x; 1.0384x over previous
//
#include <hip/hip_runtime.h>
#include <hip/hip_bf16.h>
#include <cstdint>
#include <cstddef>

typedef unsigned short u16;
typedef __bf16 bf16x8 __attribute__((ext_vector_type(8)));
typedef float f32x4 __attribute__((ext_vector_type(4)));

#define D_MODEL 1024
#define D_FF    4096
#define BATCH   2
#define SEQ     2048
#define NH      16
#define HD      64
#define ROWS    (BATCH*SEQ)   // 4096
#define QKVS    3072          // packed QKV row stride

// ---------- helpers ----------
__device__ __forceinline__ u16 f2bf(float f) {
    union { float f; uint32_t u; } v; v.f = f;
    uint32_t u = v.u;
    u += 0x7FFF + ((u >> 16) & 1);   // RNE
    return (u16)(u >> 16);
}

__device__ __forceinline__ float bf2f(u16 u) {
    union { uint32_t u; float f; } v; v.u = (uint32_t)u << 16;
    return v.f;
}

__device__ __forceinline__ uint32_t cvtpk_bf16(float lo, float hi) {
    uint32_t r;
    asm("v_cvt_pk_bf16_f32 %0, %1, %2" : "=v"(r) : "v"(lo), "v"(hi));
    return r;
}

__device__ __forceinline__ bf16x8 ldg8(const u16* p) {
    return *reinterpret_cast<const bf16x8*>(p);
}

__device__ __forceinline__ f32x4 mfma16(bf16x8 a, bf16x8 b, f32x4 c) {
    return __builtin_amdgcn_mfma_f32_16x16x32_bf16(a, b, c, 0, 0, 0);
}

__device__ __forceinline__ void gld_lds16(const void* g, void* l) {
    __builtin_amdgcn_global_load_lds(
        (const __attribute__((address_space(1))) void*)g,
        (__attribute__((address_space(3))) void*)l, 16, 0, 0);
}

// GELU, tanh-form via exp2; |err| <= ~3e-3.
__device__ __forceinline__ float gelu_f(float x) {
    float u = fmaf(0.044715f * x, x * x, x);
    float z = fminf(-2.3022036f * u, 126.0f);
    float e = __builtin_amdgcn_exp2f(z);
    return x / (1.0f + e);
}

struct alignas(8) U16x4 { u16 x, y, z, w; };

// ---------- fused prep: weight cvt (12288 blk) + LN1 (4096 blk) + bias pack (3 blk) ----------
__global__ __launch_bounds__(256) void prep(
    const float* __restrict__ s0, const float* __restrict__ s1,
    const float* __restrict__ s2, const float* __restrict__ s3,
    const float* __restrict__ s4, const float* __restrict__ s5,
    u16* __restrict__ wout,
    const float* __restrict__ x, const float* __restrict__ g1,
    const float* __restrict__ be1, u16* __restrict__ hbuf,
    const float* __restrict__ bq, const float* __restrict__ bk,
    const float* __restrict__ bv, float* __restrict__ bqkv)
{
    const size_t MM1 = 1 << 20;
    const int bid = blockIdx.x;
    const int t = threadIdx.x;

    if (bid < 12288) {
        size_t i = (size_t)bid * 1024 + t * 4;
        const float* src; size_t off;
        if      (i <     MM1) { src = s0; off = i; }
        else if (i < 2 * MM1) { src = s1; off = i - MM1; }
        else if (i < 3 * MM1) { src = s2; off = i - 2 * MM1; }
        else if (i < 4 * MM1) { src = s3; off = i - 3 * MM1; }
        else if (i < 8 * MM1) { src = s4; off = i - 4 * MM1; }
        else                  { src = s5; off = i - 8 * MM1; }
        float4 f = *reinterpret_cast<const float4*>(src + off);
        U16x4 o{ f2bf(f.x), f2bf(f.y), f2bf(f.z), f2bf(f.w) };
        *reinterpret_cast<U16x4*>(wout + i) = o;
    } else if (bid < 12288 + ROWS) {
        int row = bid - 12288;
        const float* xr = x + (size_t)row * D_MODEL;
        float4 v = *reinterpret_cast<const float4*>(xr + t * 4);
        float s = v.x + v.y + v.z + v.w;
        float q = v.x*v.x + v.y*v.y + v.z*v.z + v.w*v.w;
        #pragma unroll
        for (int off = 1; off < 64; off <<= 1) {
            s += __shfl_xor(s, off);
            q += __shfl_xor(q, off);
        }
        __shared__ float red[8];
        if ((t & 63) == 0) { red[(t >> 6) * 2] = s; red[(t >> 6) * 2 + 1] = q; }
        __syncthreads();
        float sum = red[0] + red[2] + red[4] + red[6];
        float sq  = red[1] + red[3] + red[5] + red[7];
        float mu  = sum * (1.0f / D_MODEL);
        float var = sq * (1.0f / D_MODEL) - mu * mu;
        float rstd = rsqrtf(var + 1e-6f);
        float4 gg = *reinterpret_cast<const float4*>(g1 + t * 4);
        float4 bb = *reinterpret_cast<const float4*>(be1 + t * 4);
        U16x4 o{ f2bf((v.x - mu) * rstd * gg.x + bb.x),
                 f2bf((v.y - mu) * rstd * gg.y + bb.y),
                 f2bf((v.z - mu) * rstd * gg.z + bb.z),
                 f2bf((v.w - mu) * rstd * gg.w + bb.w) };
        *reinterpret_cast<U16x4*>(hbuf + (size_t)row * D_MODEL + t * 4) = o;
    } else {
        int j = bid - (12288 + ROWS);
        const float* src = (j == 0) ? bq : (j == 1) ? bk : bv;
        float4 f = *reinterpret_cast<const float4*>(src + t * 4);
        *reinterpret_cast<float4*>(bqkv + j * 1024 + t * 4) = f;
    }
}

// ---------- LayerNorm2 (bf16 in, bf16 out) ----------
__global__ __launch_bounds__(256) void ln2_bf16(
    const u16* __restrict__ x, const float* __restrict__ g,
    const float* __restrict__ b, u16* __restrict__ out)
{
    int row = blockIdx.x;
    const u16* xr = x + (size_t)row * D_MODEL;
    int t = threadIdx.x;
    U16x4 u = *reinterpret_cast<const U16x4*>(xr + t * 4);
    float vx = bf2f(u.x), vy = bf2f(u.y), vz = bf2f(u.z), vw = bf2f(u.w);
    float s = vx + vy + vz + vw;
    float q = vx*vx + vy*vy + vz*vz + vw*vw;
    #pragma unroll
    for (int off = 1; off < 64; off <<= 1) {
        s += __shfl_xor(s, off);
        q += __shfl_xor(q, off);
    }
    __shared__ float red[8];
    if ((t & 63) == 0) { red[(t >> 6) * 2] = s; red[(t >> 6) * 2 + 1] = q; }
    __syncthreads();
    float sum = red[0] + red[2] + red[4] + red[6];
    float sq  = red[1] + red[3] + red[5] + red[7];
    float mu  = sum * (1.0f / D_MODEL);
    float var = sq * (1.0f / D_MODEL) - mu * mu;
    float rstd = rsqrtf(var + 1e-6f);
    float4 gg = *reinterpret_cast<const float4*>(g + t * 4);
    float4 bb = *reinterpret_cast<const float4*>(b + t * 4);
    U16x4 o{ f2bf((vx - mu) * rstd * gg.x + bb.x),
             f2bf((vy - mu) * rstd * gg.y + bb.y),
             f2bf((vz - mu) * rstd * gg.z + bb.z),
             f2bf((vw - mu) * rstd * gg.w + bb.w) };
    *reinterpret_cast<U16x4*>(out + (size_t)row * D_MODEL + t * 4) = o;
}

#define EPI_BF16   0
#define EPI_RESF32 1
#define EPI_GELU   2
#define EPI_PART   3
#define EPI_QKV    4
#define EPI_RESB16 5

// ---------- GEMM 128x128, m97-style single-buffer, 4 blocks/CU ----------
// NOTE: (256,4) -> VGPR 64, no spill. (256,5) spilled acc (do not raise).
// EPI_QKV: V-part blocks (bcol >= 2048) write TRANSPOSED into VT (outf)
// as one U16x4 per (mi,ni) -- replaces the vtrans kernel.
template<int EPI>
__global__ __launch_bounds__(256, 4) void gemm97(
    const u16* __restrict__ A, const u16* __restrict__ B,
    const float* __restrict__ bias, const float* __restrict__ res,
    u16* __restrict__ outb, float* __restrict__ outf,
    int M, int N, int K, int KS)
{
    __shared__ u16 As[128 * 64];
    __shared__ u16 Bs[128 * 64];
    const int t = threadIdx.x;
    const int lane = t & 63, w = t >> 6;
    const int lr = lane & 15, lg = lane >> 4;
    const int wrr = (w >> 1) * 64, wcc = (w & 1) * 64;
    const int brow = blockIdx.x * 128, bcol = blockIdx.y * 128;   // row-major
    const u16* Ag = A + (size_t)brow * KS;
    const u16* Bg = B + (size_t)bcol * KS;

    f32x4 acc[4][4] = {};
    const int NT = K >> 6;

    for (int kt = 0; kt < NT; ++kt) {
        #pragma unroll
        for (int c = 0; c < 4; ++c) {
            int f = c * 256 + t;
            int row = f >> 3, slot = f & 7;
            int sg = slot ^ (row & 7);
            gld_lds16(Ag + (size_t)row * KS + kt * 64 + sg * 8, As + f * 8);
            gld_lds16(Bg + (size_t)row * KS + kt * 64 + sg * 8, Bs + f * 8);
        }
        __syncthreads();

        bf16x8 af[4][2];
        #pragma unroll
        for (int mi = 0; mi < 4; ++mi) {
            int row = wrr + mi * 16 + lr;
            const u16* bp = As + row * 64;
            int key = row & 7;
            af[mi][0] = ldg8(bp + ((0 + lg) ^ key) * 8);
            af[mi][1] = ldg8(bp + ((4 + lg) ^ key) * 8);
        }
        __builtin_amdgcn_s_setprio(1);
        #pragma unroll
        for (int ni = 0; ni < 4; ++ni) {
            int row = wcc + ni * 16 + lr;
            const u16* bp = Bs + row * 64;
            int key = row & 7;
            bf16x8 b0 = ldg8(bp + ((0 + lg) ^ key) * 8);
            bf16x8 b1 = ldg8(bp + ((4 + lg) ^ key) * 8);
            #pragma unroll
            for (int mi = 0; mi < 4; ++mi) {
                acc[mi][ni] = mfma16(af[mi][0], b0, acc[mi][ni]);
                acc[mi][ni] = mfma16(af[mi][1], b1, acc[mi][ni]);
            }
        }
        __builtin_amdgcn_s_setprio(0);
        __syncthreads();
    }

    #pragma unroll
    for (int mi = 0; mi < 4; ++mi) {
        int r0 = brow + wrr + mi * 16 + lg * 4;
        #pragma unroll
        for (int ni = 0; ni < 4; ++ni) {
            int c = bcol + wcc + ni * 16 + lr;
            float bv = bias[c];
            if constexpr (EPI == EPI_QKV) {
                if (bcol >= 2048) {
                    // V block: transposed store into VT[(b,h)][d][s]
                    U16x4 pk{ f2bf(acc[mi][ni][0] + bv), f2bf(acc[mi][ni][1] + bv),
                              f2bf(acc[mi][ni][2] + bv), f2bf(acc[mi][ni][3] + bv) };
                    int d = c - 2048;
                    int bb = r0 >> 11, s = r0 & 2047;
                    u16* vt = (u16*)outf;
                    *reinterpret_cast<U16x4*>(
                        vt + ((size_t)(bb * NH + (d >> 6)) * HD + (d & 63)) * SEQ + s) = pk;
                    continue;
                }
            }
            #pragma unroll
            for (int j = 0; j < 4; ++j) {
                float v = acc[mi][ni][j] + bv;
                size_t idx = (size_t)(r0 + j) * N + c;
                if constexpr (EPI == EPI_GELU) {
                    outb[idx] = f2bf(gelu_f(v));
                } else if constexpr (EPI == EPI_RESF32) {
                    outf[idx] = v + res[idx];
                } else {
                    outb[idx] = f2bf(v);
                }
            }
        }
    }
}

// ---------- GEMM 128x128, 2-deep counted-vmcnt ----------
// RM=1: row-grouping. RM=0: col-grouping (FFN2).
// EPI_PART: bf16 partial at outb + kz*M*N. EPI_RESB16: bf16(v + f32 res).
template<int EPI, int RM>
__global__ __launch_bounds__(256, 2) void gemm_bt(
    const u16* __restrict__ A, const u16* __restrict__ B,
    const float* __restrict__ bias, const float* __restrict__ res,
    u16* __restrict__ outb, float* __restrict__ outf,
    int M, int N, int K, int KS)
{
    __shared__ u16 As[2][128 * 64];
    __shared__ u16 Bs[2][128 * 64];
    const int t = threadIdx.x;
    const int lane = t & 63;
    const int w = t >> 6;
    const int lr = lane & 15, lg = lane >> 4;
    const int wrr = (w >> 1) * 64, wcc = (w & 1) * 64;
    const int brow = (RM ? blockIdx.x : blockIdx.y) * 128;
    const int bcol = (RM ? blockIdx.y : blockIdx.x) * 128;
    const int kz = blockIdx.z;
    const u16* Ag = A + (size_t)brow * KS + (size_t)kz * K;
    const u16* Bg = B + (size_t)bcol * KS + (size_t)kz * K;

    f32x4 acc[4][4] = {};

    const int NT = K >> 6;

    auto stage = [&](int buf, int kt) {
        const u16* ga = Ag + kt * 64;
        const u16* gb = Bg + kt * 64;
        u16* la = As[buf];
        u16* lb = Bs[buf];
        #pragma unroll
        for (int c = 0; c < 4; ++c) {
            int f = c * 256 + t;
            int row = f >> 3, slot = f & 7;
            int sg = slot ^ (row & 7);
            gld_lds16(ga + (size_t)row * KS + sg * 8, la + f * 8);
            gld_lds16(gb + (size_t)row * KS + sg * 8, lb + f * 8);
        }
    };

    auto compute = [&](int buf) {
        const u16* la = As[buf];
        const u16* lb = Bs[buf];
        bf16x8 af[4][2];
        #pragma unroll
        for (int mi = 0; mi < 4; ++mi) {
            int row = wrr + mi * 16 + lr;
            int base = row * 64;
            af[mi][0] = *reinterpret_cast<const bf16x8*>(la + base + ((0 + lg) ^ (row & 7)) * 8);
            af[mi][1] = *reinterpret_cast<const bf16x8*>(la + base + ((4 + lg) ^ (row & 7)) * 8);
        }
        __builtin_amdgcn_s_setprio(1);
        #pragma unroll
        for (int ni = 0; ni < 4; ++ni) {
            int row = wcc + ni * 16 + lr;
            int base = row * 64;
            bf16x8 b0 = *reinterpret_cast<const bf16x8*>(lb + base + ((0 + lg) ^ (row & 7)) * 8);
            bf16x8 b1 = *reinterpret_cast<const bf16x8*>(lb + base + ((4 + lg) ^ (row & 7)) * 8);
            #pragma unroll
            for (int mi = 0; mi < 4; ++mi) {
                acc[mi][ni] = mfma16(af[mi][0], b0, acc[mi][ni]);
                acc[mi][ni] = mfma16(af[mi][1], b1, acc[mi][ni]);
            }
        }
        __builtin_amdgcn_s_setprio(0);
    };

    stage(0, 0);
    if (NT > 1) {
        stage(1, 1);
        asm volatile("s_waitcnt vmcnt(8)" ::: "memory");
    } else {
        asm volatile("s_waitcnt vmcnt(0)" ::: "memory");
    }
    __builtin_amdgcn_s_barrier();

    for (int kt = 0; kt < NT; ++kt) {
        compute(kt & 1);
        if (kt + 1 == NT) break;
        __builtin_amdgcn_s_barrier();
        if (kt + 2 < NT) {
            stage(kt & 1, kt + 2);
            asm volatile("s_waitcnt vmcnt(8)" ::: "memory");
        } else {
            asm volatile("s_waitcnt vmcnt(0)" ::: "memory");
        }
        __builtin_amdgcn_s_barrier();
    }

    #pragma unroll
    for (int mi = 0; mi < 4; ++mi) {
        int r0 = brow + wrr + mi * 16 + lg * 4;
        #pragma unroll
        for (int ni = 0; ni < 4; ++ni) {
            int c = bcol + wcc + ni * 16 + lr;
            float bv = 0.f;
            if constexpr (EPI != EPI_PART) bv = bias[c];
            #pragma unroll
            for (int j = 0; j < 4; ++j) {
                float v = acc[mi][ni][j] + bv;
                size_t idx = (size_t)(r0 + j) * N + c;
                if constexpr (EPI == EPI_GELU) {
                    outb[idx] = f2bf(gelu_f(v));
                } else if constexpr (EPI == EPI_RESF32) {
                    outf[idx] = v + res[idx];
                } else if constexpr (EPI == EPI_RESB16) {
                    outb[idx] = f2bf(v + res[idx]);
                } else if constexpr (EPI == EPI_PART) {
                    outb[idx + (size_t)kz * M * N] = f2bf(v);
                } else {
                    outb[idx] = f2bf(v);
                }
            }
        }
    }
}

// ---------- FFN2 reduce: out = bf16(p0)+bf16(p1) + bias + bf16 residual ----------
__global__ void ffn2_reduce(const u16* __restrict__ p,
                            const float* __restrict__ b2,
                            const u16* __restrict__ x2,
                            float* __restrict__ out)
{
    size_t i = ((size_t)blockIdx.x * 256 + threadIdx.x) * 4;
    U16x4 a0 = *reinterpret_cast<const U16x4*>(p + i);
    U16x4 a1 = *reinterpret_cast<const U16x4*>(p + (size_t)ROWS * D_MODEL + i);
    U16x4 rr = *reinterpret_cast<const U16x4*>(x2 + i);
    float4 bb = *reinterpret_cast<const float4*>(b2 + (i & (D_MODEL - 1)));
    float4 o;
    o.x = bf2f(a0.x) + bf2f(a1.x) + bf2f(rr.x) + bb.x;
    o.y = bf2f(a0.y) + bf2f(a1.y) + bf2f(rr.y) + bb.y;
    o.z = bf2f(a0.z) + bf2f(a1.z) + bf2f(rr.z) + bb.z;
    o.w = bf2f(a0.w) + bf2f(a1.w) + bf2f(rr.w) + bb.w;
    *reinterpret_cast<float4*>(out + i) = o;
}

// ---------- causal flash attention v8: 1 barrier/tile, K 3-buf / V 2-buf ----------
#define QBLK  64
#define KVBLK 64

__global__ __launch_bounds__(256, 3) void attn8(
    const u16* __restrict__ QKV, const u16* __restrict__ VT,
    u16* __restrict__ O)
{
    __shared__ u16 Ks[3][64 * 64];    // [kv][d], swizzle key (kv>>2)&7
    __shared__ u16 Vs[2][64 * 64];    // [d][kv], swizzle key d&7
    __shared__ u16 Pl[4][16 * 72];    // per-wave P[q][kv], stride 72

    const int i  = blockIdx.x;            // 0..15
    const int bh = blockIdx.y;
    const int b = bh >> 4, h = bh & 15;
    const int qta = 31 - i;               // heavy q-tile
    const int qtb = i;                    // light q-tile
    const int q0a = qta * QBLK, q0b = qtb * QBLK;
    const int t = threadIdx.x;
    const int lane = t & 63, w = t >> 6;
    const int lr = lane & 15, lg = lane >> 4;

    const size_t rowbase = (size_t)b * SEQ;
    const u16* Qg = QKV + rowbase * QKVS + h * HD;
    const u16* Kg = Qg + 1024;
    const u16* Vg = VT + (size_t)bh * HD * SEQ;

    const u16* qpa = Qg + (size_t)(q0a + w * 16 + lr) * QKVS;
    const u16* qpb = Qg + (size_t)(q0b + w * 16 + lr) * QKVS;
    bf16x8 qa0 = ldg8(qpa + lg * 8), qa1 = ldg8(qpa + 32 + lg * 8);
    bf16x8 qb0 = ldg8(qpb + lg * 8), qb1 = ldg8(qpb + 32 + lg * 8);

    f32x4 oa[4] = {}, ob[4] = {};
    float lsa[4] = {}, lsb[4] = {};

    const int ntiles = qta + 1;           // 17..32 (>= 3 always)
    u16* Pw = Pl[w];
    const float SC = 0.125f * 1.44269504089f;

    auto stageK = [&](int buf, int tt) {
        const int kv0 = tt * KVBLK;
        #pragma unroll
        for (int c = 0; c < 2; ++c) {
            int f = c * 256 + t;
            int row = f >> 3, slot = f & 7;
            int sgk = slot ^ ((row >> 2) & 7);
            gld_lds16(Kg + (size_t)(kv0 + row) * QKVS + sgk * 8, Ks[buf] + f * 8);
        }
    };
    auto stageV = [&](int buf, int tt) {
        const int kv0 = tt * KVBLK;
        #pragma unroll
        for (int c = 0; c < 2; ++c) {
            int f = c * 256 + t;
            int row = f >> 3, slot = f & 7;
            int sgv = slot ^ (row & 7);
            gld_lds16(Vg + (size_t)row * SEQ + kv0 + sgv * 8, Vs[buf] + f * 8);
        }
    };

    auto qtile = [&](bf16x8 qf0, bf16x8 qf1, f32x4* o, float* ls,
                     int q0, int kv0, bool diag, const u16* kb, const u16* vb) {
        f32x4 s[4] = {};
        __builtin_amdgcn_s_setprio(1);
        #pragma unroll
        for (int ni = 0; ni < 4; ++ni) {
            int row = lr * 4 + ni;
            const u16* base = kb + row * 64;
            int key = (row >> 2) & 7;
            bf16x8 k0 = *reinterpret_cast<const bf16x8*>(base + ((0 + lg) ^ key) * 8);
            bf16x8 k1 = *reinterpret_cast<const bf16x8*>(base + ((4 + lg) ^ key) * 8);
            s[ni] = mfma16(qf0, k0, s[ni]);
            s[ni] = mfma16(qf1, k1, s[ni]);
        }
        __builtin_amdgcn_s_setprio(0);

        #pragma unroll
        for (int j = 0; j < 4; ++j) {
            int qi = q0 + w * 16 + lg * 4 + j;
            float p0 = __builtin_amdgcn_exp2f(s[0][j] * SC);
            float p1 = __builtin_amdgcn_exp2f(s[1][j] * SC);
            float p2 = __builtin_amdgcn_exp2f(s[2][j] * SC);
            float p3 = __builtin_amdgcn_exp2f(s[3][j] * SC);
            if (diag) {
                int kvb = kv0 + lr * 4;
                p0 = (kvb     <= qi) ? p0 : 0.f;
                p1 = (kvb + 1 <= qi) ? p1 : 0.f;
                p2 = (kvb + 2 <= qi) ? p2 : 0.f;
                p3 = (kvb + 3 <= qi) ? p3 : 0.f;
            }
            ls[j] += (p0 + p1) + (p2 + p3);
            uint2 pk = make_uint2(cvtpk_bf16(p0, p1), cvtpk_bf16(p2, p3));
            *reinterpret_cast<uint2*>(&Pw[(lg * 4 + j) * 72 + lr * 4]) = pk;
        }

        bf16x8 pa0 = *reinterpret_cast<const bf16x8*>(Pw + lr * 72 + lg * 8);
        bf16x8 pa1 = *reinterpret_cast<const bf16x8*>(Pw + lr * 72 + 32 + lg * 8);
        __builtin_amdgcn_s_setprio(1);
        #pragma unroll
        for (int ni = 0; ni < 4; ++ni) {
            int row = ni * 16 + lr;
            const u16* base = vb + row * 64;
            bf16x8 v0 = *reinterpret_cast<const bf16x8*>(base + ((0 + lg) ^ (row & 7)) * 8);
            bf16x8 v1 = *reinterpret_cast<const bf16x8*>(base + ((4 + lg) ^ (row & 7)) * 8);
            o[ni] = mfma16(pa0, v0, o[ni]);
            o[ni] = mfma16(pa1, v1, o[ni]);
        }
        __builtin_amdgcn_s_setprio(0);
    };

    // prologue: V(0), K(0), K(1) in flight (order matters for vmcnt FIFO)
    stageV(0, 0);
    stageK(0, 0);
    stageK(1, 1);

    for (int tt = 0; tt < ntiles; ++tt) {
        __builtin_amdgcn_s_barrier();       // iter tt-1 compute complete
        if (tt + 1 < ntiles) stageV((tt + 1) & 1, tt + 1);
        if (tt + 2 < ntiles) stageK((tt + 2) % 3, tt + 2);
        if (tt + 2 < ntiles)
            asm volatile("s_waitcnt vmcnt(6)" ::: "memory");  // K(tt),V(tt) done
        else if (tt + 1 < ntiles)
            asm volatile("s_waitcnt vmcnt(4)" ::: "memory");
        else
            asm volatile("s_waitcnt vmcnt(0)" ::: "memory");

        const int kv0 = tt * KVBLK;
        const u16* kb = Ks[tt % 3];
        const u16* vb = Vs[tt & 1];

        qtile(qa0, qa1, oa, lsa, q0a, kv0, tt == qta, kb, vb);
        if (tt <= qtb)
            qtile(qb0, qb1, ob, lsb, q0b, kv0, tt == qtb, kb, vb);
    }

    #pragma unroll
    for (int j = 0; j < 4; ++j) {
        float va = lsa[j], vb2 = lsb[j];
        va += __shfl_xor(va, 1); vb2 += __shfl_xor(vb2, 1);
        va += __shfl_xor(va, 2); vb2 += __shfl_xor(vb2, 2);
        va += __shfl_xor(va, 4); vb2 += __shfl_xor(vb2, 4);
        va += __shfl_xor(va, 8); vb2 += __shfl_xor(vb2, 8);
        lsa[j] = va; lsb[j] = vb2;
    }

    u16* Oa = O + (rowbase + q0a + w * 16) * D_MODEL + h * HD;
    u16* Ob = O + (rowbase + q0b + w * 16) * D_MODEL + h * HD;
    #pragma unroll
    for (int j = 0; j < 4; ++j) {
        float inva = 1.0f / lsa[j];
        float invb = 1.0f / lsb[j];
        int r = (lg * 4 + j) * D_MODEL;
        #pragma unroll
        for (int ni = 0; ni < 4; ++ni) {
            Oa[r + ni * 16 + lr] = f2bf(oa[ni][j] * inva);
            Ob[r + ni * 16 + lr] = f2bf(ob[ni][j] * invb);
        }
    }
}

// ---------- launch ----------
extern "C" void kernel_launch(void* const* d_in, const int* in_sizes, int n_in,
                              void* d_out, int out_size, void* d_ws, size_t ws_size,
                              hipStream_t stream)
{
    (void)in_sizes; (void)n_in; (void)out_size; (void)ws_size;
    const float* x   = (const float*)d_in[0];
    const float* Wq  = (const float*)d_in[2];
    const float* bq  = (const float*)d_in[3];
    const float* Wk  = (const float*)d_in[4];
    const float* bk  = (const float*)d_in[5];
    const float* Wv  = (const float*)d_in[6];
    const float* bv  = (const float*)d_in[7];
    const float* Wo  = (const float*)d_in[8];
    const float* bo  = (const float*)d_in[9];
    const float* g1  = (const float*)d_in[10];
    const float* be1 = (const float*)d_in[11];
    const float* g2  = (const float*)d_in[12];
    const float* be2 = (const float*)d_in[13];
    const float* W1  = (const float*)d_in[14];
    const float* b1  = (const float*)d_in[15];
    const float* W2  = (const float*)d_in[16];
    const float* b2  = (const float*)d_in[17];
    float* out = (float*)d_out;

    const size_t MM = 1 << 20;   // 1M elems
    u16* Wqkv_b = (u16*)d_ws;            // 3M u16 (Wq,Wk,Wv packed [3072][1024])
    u16* Wo_b = Wqkv_b + 3 * MM;
    u16* W1_b = Wo_b + MM;               // 4M
    u16* W2_b = W1_b + 4 * MM;           // 4M
    u16* hbuf = W2_b + 4 * MM;           // 4M (LN out)
    u16* QKVb = hbuf + 4 * MM;           // 12M  [4096][3072] (V part unused)
    u16* ctx  = QKVb + 12 * MM;          // 4M
    u16* ffn1 = ctx + 4 * MM;            // 16M
    u16* x2   = ffn1 + 16 * MM;          // 4M bf16 residual stream
    float* bqkv = (float*)(x2 + 4 * MM); // 3072 f32
    u16* VTb  = (u16*)(bqkv + 4096);     // 4M u16 [32 bh][64 d][2048 s]
    u16* fpart = QKVb;                   // FFN2 bf16 partials alias QKV (dead)

    // fused prep: weight cvt + LN1 + bias pack (one launch)
    prep<<<12288 + ROWS + 3, 256, 0, stream>>>(Wq, Wk, Wv, Wo, W1, W2, Wqkv_b,
                                               x, g1, be1, hbuf, bq, bk, bv, bqkv);

    // fused QKV projection; V part written transposed into VTb by epilogue
    dim3 gqkv(ROWS / 128, QKVS / 128);
    gemm97<EPI_QKV><<<gqkv, 256, 0, stream>>>(hbuf, Wqkv_b, bqkv, nullptr,
                                              QKVb, (float*)VTb, ROWS, QKVS, 1024, 1024);

    // attention: paired q-tiles, 1-barrier pipeline, 512 equal blocks
    dim3 ga(SEQ / QBLK / 2, BATCH * NH);      // (16, 32)
    attn8<<<ga, 256, 0, stream>>>(QKVb, VTb, ctx);

    // Wo projection + residual -> bf16 x2 (row-major grid (32, 8))
    dim3 gq(ROWS / 128, D_MODEL / 128);
    gemm_bt<EPI_RESB16, 1><<<gq, 256, 0, stream>>>(ctx, Wo_b, bo, x, x2, nullptr,
                                                   ROWS, D_MODEL, 1024, 1024);

    // LN2 (bf16 in)
    ln2_bf16<<<ROWS, 256, 0, stream>>>(x2, g2, be2, hbuf);

    // FFN1 + GELU: m97 single-buffer, row-major grid (32, 32)
    dim3 gf1(ROWS / 128, D_FF / 128);
    gemm97<EPI_GELU><<<gf1, 256, 0, stream>>>(hbuf, W1_b, b1, nullptr, ffn1, nullptr,
                                              ROWS, D_FF, 1024, 1024);

    // FFN2 split-K2: col-major grid, bf16 partials; reduce adds bias+residual
    dim3 gf2(D_MODEL / 128, ROWS / 128, 2);
    gemm_bt<EPI_PART, 0><<<gf2, 256, 0, stream>>>(ffn1, W2_b, nullptr, nullptr,
                                                  fpart, nullptr, ROWS, D_MODEL, 2048, 4096);
    ffn2_reduce<<<(ROWS * D_MODEL) / 1024, 256, 0, stream>>>(fpart, b2, x2, out);
}